// Round 6
// baseline (242.121 us; speedup 1.0000x reference)
//
#include <hip/hip_runtime.h>
#include <math.h>

#define NW   12
#define DIM  4096
#define TPB  512
#define NR   8      // amplitudes per thread

// force a wave-uniform float into an SGPR (drops VGPR pressure; v_fma takes 1 SGPR src)
__device__ __forceinline__ float rfl(float f) {
    return __int_as_float(__builtin_amdgcn_readfirstlane(__float_as_int(f)));
}
__device__ __forceinline__ float2 rfl2(float2 f) { return make_float2(rfl(f.x), rfl(f.y)); }

__device__ __forceinline__ float2 cmul(float2 a, float2 b) {
    return make_float2(a.x * b.x - a.y * b.y, a.x * b.y + a.y * b.x);
}
__device__ __forceinline__ float2 f2add(float2 a, float2 b) {
    return make_float2(a.x + b.x, a.y + b.y);
}

// acc = sum_j c_j * x_j (complex), 4 terms, all scalar args (SROA-safe)
__device__ __forceinline__ float2 cfma4(float2 c0, float2 x0, float2 c1, float2 x1,
                                        float2 c2, float2 x2, float2 c3, float2 x3) {
    float ax = 0.f, ay = 0.f;
    ax = fmaf(c0.x, x0.x, fmaf(-c0.y, x0.y, ax)); ay = fmaf(c0.x, x0.y, fmaf(c0.y, x0.x, ay));
    ax = fmaf(c1.x, x1.x, fmaf(-c1.y, x1.y, ax)); ay = fmaf(c1.x, x1.y, fmaf(c1.y, x1.x, ay));
    ax = fmaf(c2.x, x2.x, fmaf(-c2.y, x2.y, ax)); ay = fmaf(c2.x, x2.y, fmaf(c2.y, x2.x, ay));
    ax = fmaf(c3.x, x3.x, fmaf(-c3.y, x3.y, ax)); ay = fmaf(c3.x, x3.y, fmaf(c3.y, x3.x, ay));
    return make_float2(ax, ay);
}

// (a,b) <- M (a,b), complex 2x2 (M components in SGPRs)
__device__ __forceinline__ void cgate(float2& a, float2& b,
        const float2 m00, const float2 m01, const float2 m10, const float2 m11) {
    float2 na, nb;
    na.x = fmaf(m00.x, a.x, fmaf(-m00.y, a.y, fmaf(m01.x, b.x, -m01.y * b.y)));
    na.y = fmaf(m00.x, a.y, fmaf( m00.y, a.x, fmaf(m01.x, b.y,  m01.y * b.x)));
    nb.x = fmaf(m10.x, a.x, fmaf(-m10.y, a.y, fmaf(m11.x, b.x, -m11.y * b.y)));
    nb.y = fmaf(m10.x, a.y, fmaf( m10.y, a.x, fmaf(m11.x, b.y,  m11.y * b.x)));
    a = na; b = nb;
}

// cross-lane xor exchange: DPP quad_perm for masks 1,2 (VALU pipe), shfl otherwise
template<int B>
__device__ __forceinline__ float shflx(float x) {
    if constexpr (B == 0) {
        int i = __float_as_int(x);
        return __int_as_float(__builtin_amdgcn_update_dpp(i, i, 0xB1, 0xF, 0xF, true)); // quad_perm 1,0,3,2
    } else if constexpr (B == 1) {
        int i = __float_as_int(x);
        return __int_as_float(__builtin_amdgcn_update_dpp(i, i, 0x4E, 0xF, 0xF, true)); // quad_perm 2,3,0,1
    } else {
        return __shfl_xor(x, 1 << B, 64);
    }
}

// gate M on register bit J (z bit 9+J): pure VALU
template<int J>
__device__ __forceinline__ void reg_gate(float2* v,
        const float2 m00, const float2 m01, const float2 m10, const float2 m11) {
#pragma unroll
    for (int m = 0; m < 4; ++m) {
        int r0 = ((m >> J) << (J + 1)) | (m & ((1 << J) - 1));
        cgate(v[r0], v[r0 | (1 << J)], m00, m01, m10, m11);
    }
}

// gate M on lane bit B (z bit B): cross-lane, no barrier
template<int B>
__device__ __forceinline__ void lane_gate(float2* v, int lane,
        const float2 m00, const float2 m01, const float2 m10, const float2 m11) {
    const bool hib = (lane >> B) & 1;
    const float cax = hib ? m11.x : m00.x, cay = hib ? m11.y : m00.y;
    const float cbx = hib ? m10.x : m01.x, cby = hib ? m10.y : m01.y;
#pragma unroll
    for (int r = 0; r < NR; ++r) {
        float px = shflx<B>(v[r].x);
        float py = shflx<B>(v[r].y);
        float nx = fmaf(cax, v[r].x, fmaf(-cay, v[r].y, fmaf(cbx, px, -cby * py)));
        float ny = fmaf(cax, v[r].y, fmaf( cay, v[r].x, fmaf(cbx, py,  cby * px)));
        v[r] = make_float2(nx, ny);
    }
}

// fused: gates on wave bits 6,7,8 (M on each) + Gray CNOT permutation new[z]=old[z^(z>>1)],
// one LDS round trip.  z = (r<<9)|tid; y = z^(z>>1); source addr = (y & ~0x1C0)|(jj<<6).
// coefficient(jj) = M[y8,jj2]*M[y7,jj1]*M[y6,jj0]; y6,y7 wave-uniform, y8 = tid8 ^ r0
// -> two wave-uniform coefficient sets (even/odd r), pinned to SGPRs.
__device__ __forceinline__ void exchange(float2* psis, float2* v, int tid, int gw,
        const float2 m00, const float2 m01, const float2 m10, const float2 m11) {
    __syncthreads();                 // protect prior readers of psis
#pragma unroll
    for (int r = 0; r < NR; ++r) psis[(r << 9) | tid] = v[r];
    __syncthreads();

    const int y6 = (gw >> 6) & 1;    // tid6^tid7 (wave-uniform)
    const int y7 = (gw >> 7) & 1;    // tid7^tid8 (wave-uniform)
    const int t8 = (tid >> 8) & 1;   // y8 for even r; odd r flips (wave-uniform)
    const float2 M6_0 = y6 ? m10 : m00, M6_1 = y6 ? m11 : m01;
    const float2 M7_0 = y7 ? m10 : m00, M7_1 = y7 ? m11 : m01;
    const float2 M8E0 = t8 ? m10 : m00, M8E1 = t8 ? m11 : m01;
    const float2 M8O0 = t8 ? m00 : m10, M8O1 = t8 ? m01 : m11;
    const float2 p00 = cmul(M7_0, M6_0), p01 = cmul(M7_0, M6_1);
    const float2 p10 = cmul(M7_1, M6_0), p11 = cmul(M7_1, M6_1);
    const float2 e0 = rfl2(cmul(M8E0, p00)), e1 = rfl2(cmul(M8E0, p01));
    const float2 e2 = rfl2(cmul(M8E0, p10)), e3 = rfl2(cmul(M8E0, p11));
    const float2 e4 = rfl2(cmul(M8E1, p00)), e5 = rfl2(cmul(M8E1, p01));
    const float2 e6 = rfl2(cmul(M8E1, p10)), e7 = rfl2(cmul(M8E1, p11));
    const float2 o0 = rfl2(cmul(M8O0, p00)), o1 = rfl2(cmul(M8O0, p01));
    const float2 o2 = rfl2(cmul(M8O0, p10)), o3 = rfl2(cmul(M8O0, p11));
    const float2 o4 = rfl2(cmul(M8O1, p00)), o5 = rfl2(cmul(M8O1, p01));
    const float2 o6 = rfl2(cmul(M8O1, p10)), o7 = rfl2(cmul(M8O1, p11));

#pragma unroll
    for (int h = 0; h < 4; ++h) {
        const int re = h << 1;
        const int baseE = (((re << 9) ^ (re << 8)) ^ gw) & ~0x1C0;
        const int baseO = baseE ^ 0x200;
        float2 x0 = psis[baseE],         x1 = psis[baseE | 0x040];
        float2 x2 = psis[baseE | 0x080], x3 = psis[baseE | 0x0C0];
        float2 x4 = psis[baseE | 0x100], x5 = psis[baseE | 0x140];
        float2 x6 = psis[baseE | 0x180], x7 = psis[baseE | 0x1C0];
        v[re] = f2add(cfma4(e0, x0, e1, x1, e2, x2, e3, x3),
                      cfma4(e4, x4, e5, x5, e6, x6, e7, x7));
        float2 w0 = psis[baseO],         w1 = psis[baseO | 0x040];
        float2 w2 = psis[baseO | 0x080], w3 = psis[baseO | 0x0C0];
        float2 w4 = psis[baseO | 0x100], w5 = psis[baseO | 0x140];
        float2 w6 = psis[baseO | 0x180], w7 = psis[baseO | 0x1C0];
        v[re | 1] = f2add(cfma4(o0, w0, o1, w1, o2, w2, o3, w3),
                          cfma4(o4, w4, o5, w5, o6, w6, o7, w7));
    }
}

// 512 threads: 8 amps/thread (16 VGPRs of state) -> total demand ~50 VGPRs, fits the
// 64-VGPR / 8-waves-per-EU budget the allocator insists on (R3-R5: hints ignored).
__global__ __launch_bounds__(TPB, 8)
void qmnist_kernel(const float* __restrict__ x,  const float* __restrict__ W1,
                   const float* __restrict__ b1, const float* __restrict__ ryp,
                   const float* __restrict__ rzp, const float* __restrict__ W2,
                   const float* __restrict__ b2, float* __restrict__ out) {
    __shared__ float2 psis[DIM];
    __shared__ float  wred[8 * NW];
    __shared__ float  encc[NW], encs[NW];
    __shared__ float  zfin[NW];

    const int tid  = threadIdx.x;
    const int blk  = blockIdx.x;
    const int lane = tid & 63;
    const int wave = tid >> 6;
    const int gw   = tid ^ (tid >> 1);          // Gray of tid (bits 0..8)

    // ---------------- phase 0: feat = x[blk] @ W1^T + b1 -> encoding angles
    float acc[NW];
#pragma unroll
    for (int w = 0; w < NW; ++w) acc[w] = 0.f;
    const float* xrow = x + (size_t)blk * 784;
    for (int j = tid; j < 784; j += TPB) {
        float xv = xrow[j];
#pragma unroll
        for (int w = 0; w < NW; ++w)
            acc[w] = fmaf(xv, W1[w * 784 + j], acc[w]);
    }
#pragma unroll
    for (int w = 0; w < NW; ++w) {
        float s = acc[w];
        s += __shfl_down(s, 32);
        s += __shfl_down(s, 16);
        s += __shfl_down(s, 8);
        s += __shfl_down(s, 4);
        s += __shfl_down(s, 2);
        s += __shfl_down(s, 1);
        if (lane == 0) wred[wave * NW + w] = s;
    }
    __syncthreads();
    if (tid < NW) {
        float feat = b1[tid];
#pragma unroll
        for (int q = 0; q < 8; ++q) feat += wred[q * NW + tid];
        float a = tanhf(feat) * 3.14159265358979323846f;
        float h = 0.5f * a;
        encc[tid] = cosf(h);
        encs[tid] = sinf(h);
    }
    __syncthreads();

    // ---------------- init product state directly into registers
    // z = (r<<9) | tid ; z bit b <-> wire (11-b)
    float hi = 1.f;
#pragma unroll
    for (int b = 0; b < 9; ++b) {
        int w = 11 - b;
        hi *= ((tid >> b) & 1) ? encs[w] : encc[w];
    }
    float2 v[NR];
#pragma unroll
    for (int r = 0; r < NR; ++r) {
        float f = hi;
        f *= (r & 1) ? encs[2] : encc[2];   // z bit 9  -> wire 2
        f *= (r & 2) ? encs[1] : encc[1];   // z bit 10 -> wire 1
        f *= (r & 4) ? encs[0] : encc[0];   // z bit 11 -> wire 0
        v[r] = make_float2(f, 0.f);
    }

    // ---------------- fused variational gate  M = RZ(rz) * RY(ry), grid-uniform -> SGPRs
    const float ry = ryp[0], rz = rzp[0];
    const float c  = cosf(0.5f * ry), s  = sinf(0.5f * ry);
    const float zc = cosf(0.5f * rz), zs = sinf(0.5f * rz);
    const float2 m00 = rfl2(make_float2( c * zc, -c * zs));
    const float2 m01 = rfl2(make_float2(-s * zc,  s * zs));
    const float2 m10 = rfl2(make_float2( s * zc,  s * zs));
    const float2 m11 = rfl2(make_float2( c * zc,  c * zs));

    for (int layer = 0; layer < 3; ++layer) {
        // register-bit gates (z bits 9..11), pure VALU
        reg_gate<0>(v, m00, m01, m10, m11);
        reg_gate<1>(v, m00, m01, m10, m11);
        reg_gate<2>(v, m00, m01, m10, m11);
        // lane-bit gates (z bits 0..5), DPP / shuffle, no barriers
        lane_gate<0>(v, lane, m00, m01, m10, m11);
        lane_gate<1>(v, lane, m00, m01, m10, m11);
        lane_gate<2>(v, lane, m00, m01, m10, m11);
        lane_gate<3>(v, lane, m00, m01, m10, m11);
        lane_gate<4>(v, lane, m00, m01, m10, m11);
        lane_gate<5>(v, lane, m00, m01, m10, m11);
        // wave-bit gates (z bits 6,7,8) + Gray permutation, one LDS round trip
        exchange(psis, v, tid, gw, m00, m01, m10, m11);
    }

    // ---------------- measure <Z_w>; state is in registers
    float t_total = 0.f, s2 = 0.f, s1 = 0.f, s0 = 0.f;
#pragma unroll
    for (int r = 0; r < NR; ++r) {
        float p = fmaf(v[r].x, v[r].x, v[r].y * v[r].y);
        t_total += p;
        if (r & 1) s2 += p;   // z bit 9  -> wire 2
        if (r & 2) s1 += p;   // z bit 10 -> wire 1
        if (r & 4) s0 += p;   // z bit 11 -> wire 0
    }
    float contrib[NW];
    contrib[2] = t_total - 2.f * s2;
    contrib[1] = t_total - 2.f * s1;
    contrib[0] = t_total - 2.f * s0;
#pragma unroll
    for (int b = 0; b < 9; ++b) {
        int w = 11 - b;                      // wires 11..3 from tid bits 0..8
        contrib[w] = ((tid >> b) & 1) ? -t_total : t_total;
    }
#pragma unroll
    for (int w = 0; w < NW; ++w) {
        float sv = contrib[w];
        sv += __shfl_down(sv, 32);
        sv += __shfl_down(sv, 16);
        sv += __shfl_down(sv, 8);
        sv += __shfl_down(sv, 4);
        sv += __shfl_down(sv, 2);
        sv += __shfl_down(sv, 1);
        if (lane == 0) wred[wave * NW + w] = sv;
    }
    __syncthreads();
    if (tid < NW) {
        float z = 0.f;
#pragma unroll
        for (int q = 0; q < 8; ++q) z += wred[q * NW + tid];
        zfin[tid] = z;
    }
    __syncthreads();

    // ---------------- head: out = z @ W2^T + b2
    if (tid < 10) {
        float o = b2[tid];
#pragma unroll
        for (int w = 0; w < NW; ++w)
            o = fmaf(zfin[w], W2[tid * NW + w], o);
        out[(size_t)blk * 10 + tid] = o;
    }
}

extern "C" void kernel_launch(void* const* d_in, const int* in_sizes, int n_in,
                              void* d_out, int out_size, void* d_ws, size_t ws_size,
                              hipStream_t stream) {
    const float* x   = (const float*)d_in[0];
    const float* W1  = (const float*)d_in[1];
    const float* b1  = (const float*)d_in[2];
    const float* ry  = (const float*)d_in[3];
    const float* rz  = (const float*)d_in[4];
    const float* W2  = (const float*)d_in[5];
    const float* b2  = (const float*)d_in[6];
    float* out = (float*)d_out;

    const int batch = in_sizes[0] / 784;   // 2048
    qmnist_kernel<<<batch, TPB, 0, stream>>>(x, W1, b1, ry, rz, W2, b2, out);
}